// Round 2
// baseline (412.644 us; speedup 1.0000x reference)
//
#include <hip/hip_runtime.h>

// Trilinear interpolation: input [16][128][128][128] fp32, coords [N][3] in [-1,1],
// out [16][N] fp32.
//
// R7: 128 B quad-cell layout. Cell (x,y,z) = 128 B holding 16-ch bf16 payloads of
// the 2x2 voxel block (y,y+1)x(z,z+1) (clamped at the high edge):
//   slot0 = v(y,z) | slot1 = v(y,z+1) | slot2 = v(y+1,z) | slot3 = v(y+1,z+1)
// A query reads exactly TWO aligned 128 B cells (x0,x1) = 256 B/pt, 100% payload
// utilization, in 2 sequential-burst transactions instead of R6's 4 random 64 B
// lines. Attacks the ~3.5 TB/s random-64B transaction wall seen in R5/R6.
// ws = 128^3 * 128 B = 256 MiB; falls back to R6 pair layout (134 MiB) then to
// direct fp32 gather if the workspace is smaller.

#define GD   128
#define NCH  16
constexpr int VOX = GD * GD * GD;

__device__ __forceinline__ unsigned short f2bf_rne(float f) {
    unsigned u = __builtin_bit_cast(unsigned, f);
    u = u + 0x7fffu + ((u >> 16) & 1u);   // round-nearest-even
    return (unsigned short)(u >> 16);
}

// ---------- R7 transpose: one voxel per thread, scatter own 32 B into 4 cells ----------
__global__ __launch_bounds__(256) void transpose_quad_k(const float* __restrict__ in,
                                                        uint4* __restrict__ ws) {
    int s = blockIdx.x * 256 + threadIdx.x;   // voxel linear index == cell linear index
    int z = s & (GD - 1);
    int y = (s >> 7) & (GD - 1);

    float a[NCH];
#pragma unroll
    for (int c = 0; c < NCH; ++c)
        a[c] = __builtin_nontemporal_load(in + (size_t)c * VOX + s);

    unsigned w[8];
#pragma unroll
    for (int k = 0; k < 8; ++k)
        w[k] = (unsigned)f2bf_rne(a[2 * k + 0]) | ((unsigned)f2bf_rne(a[2 * k + 1]) << 16);

    uint4 lo = make_uint4(w[0], w[1], w[2], w[3]);
    uint4 hi = make_uint4(w[4], w[5], w[6], w[7]);

    // cell slot j occupies uint4 indices {2j, 2j+1}; cell stride = 8 uint4 = 128 B
    uint4* o = ws + (size_t)s * 8;
    o[0] = lo; o[1] = hi;                                  // slot0 of (y,z): self
    if (z > 0)          { uint4* p = ws + (size_t)(s - 1) * 8;      p[2] = lo; p[3] = hi; }
    if (y > 0)          { uint4* p = ws + (size_t)(s - GD) * 8;     p[4] = lo; p[5] = hi; }
    if (y > 0 && z > 0) { uint4* p = ws + (size_t)(s - GD - 1) * 8; p[6] = lo; p[7] = hi; }
    // high-edge clamp fills (rare; defensive for coords hitting exactly +1):
    if (z == GD - 1)              { o[2] = lo; o[3] = hi; }
    if (y == GD - 1)              { o[4] = lo; o[5] = hi; }
    if (y == GD - 1 && z > 0)     { uint4* p = ws + (size_t)(s - 1) * 8;  p[6] = lo; p[7] = hi; }
    if (z == GD - 1 && y > 0)     { uint4* p = ws + (size_t)(s - GD) * 8; p[6] = lo; p[7] = hi; }
    if (y == GD - 1 && z == GD - 1) { o[6] = lo; o[7] = hi; }
}

// ---------- R7 interp: 2 cells x 128 B, all 16 dwordx4 loads batched ----------
__global__ __launch_bounds__(256) void interp_quad_k(const uint4* __restrict__ ws,
                                                     const float* __restrict__ coords,
                                                     float* __restrict__ out, int N) {
    int n = blockIdx.x * 256 + threadIdx.x;
    if (n >= N) return;

    float cx = (coords[3 * n + 0] + 1.0f) * 0.5f * (float)(GD - 1);
    float cy = (coords[3 * n + 1] + 1.0f) * 0.5f * (float)(GD - 1);
    float cz = (coords[3 * n + 2] + 1.0f) * 0.5f * (float)(GD - 1);

    float fx = floorf(cx), fy = floorf(cy), fz = floorf(cz);
    float tx = cx - fx, ty = cy - fy, tz = cz - fz;
    int ix = (int)fx, iy = (int)fy, iz = (int)fz;

    int ix0 = min(max(ix,     0), GD - 1), ix1 = min(max(ix + 1, 0), GD - 1);
    int iy0 = min(max(iy,     0), GD - 1);   // cell provides y and clamped y+1
    int iz0 = min(max(iz,     0), GD - 1);   // cell provides z and clamped z+1

    float wx0 = 1.0f - tx, wx1 = tx;
    float wy0 = 1.0f - ty, wy1 = ty;
    float wz0 = 1.0f - tz, wz1 = tz;

    const uint4* pA = ws + ((size_t)(ix0 * GD + iy0) * GD + iz0) * 8;
    const uint4* pB = ws + ((size_t)(ix1 * GD + iy0) * GD + iz0) * 8;

    // batch all 16 dwordx4 loads (2 x 128 B sequential) for max MLP
    uint4 q[16];
#pragma unroll
    for (int j = 0; j < 8; ++j) { q[j] = pA[j]; q[8 + j] = pB[j]; }

    // slot weights (y,z): 0:(y0,z0) 1:(y0,z1) 2:(y1,z0) 3:(y1,z1)
    float wyz[4] = { wy0 * wz0, wy0 * wz1, wy1 * wz0, wy1 * wz1 };
    float wxc[2] = { wx0, wx1 };

    float acc[NCH];
#pragma unroll
    for (int c = 0; c < NCH; ++c) acc[c] = 0.0f;

#pragma unroll
    for (int xc = 0; xc < 2; ++xc) {
#pragma unroll
        for (int sl = 0; sl < 4; ++sl) {
            const uint4 qa = q[xc * 8 + sl * 2 + 0];
            const uint4 qb = q[xc * 8 + sl * 2 + 1];
            unsigned u[8] = { qa.x, qa.y, qa.z, qa.w, qb.x, qb.y, qb.z, qb.w };
            float wv = wxc[xc] * wyz[sl];
#pragma unroll
            for (int k = 0; k < 8; ++k) {
                float vlo = __builtin_bit_cast(float, u[k] << 16);
                float vhi = __builtin_bit_cast(float, u[k] & 0xffff0000u);
                acc[2 * k + 0] += wv * vlo;
                acc[2 * k + 1] += wv * vhi;
            }
        }
    }

#pragma unroll
    for (int c = 0; c < NCH; ++c)
        __builtin_nontemporal_store(acc[c], out + (size_t)c * N + n);  // never re-read
}

// ---------- R6 fallback: pair layout (64 B lines), ws = 134 MiB ----------
__global__ __launch_bounds__(256) void transpose_half_k(const float* __restrict__ in,
                                                        uint4* __restrict__ ws) {
    int s = blockIdx.x * 256 + threadIdx.x;
    int z = s & (GD - 1);

    float a[NCH];
#pragma unroll
    for (int c = 0; c < NCH; ++c)
        a[c] = __builtin_nontemporal_load(in + (size_t)c * VOX + s);

    unsigned w[8];
#pragma unroll
    for (int k = 0; k < 8; ++k)
        w[k] = (unsigned)f2bf_rne(a[2 * k + 0]) | ((unsigned)f2bf_rne(a[2 * k + 1]) << 16);

    uint4 lo = make_uint4(w[0], w[1], w[2], w[3]);
    uint4 hi = make_uint4(w[4], w[5], w[6], w[7]);

    uint4* o = ws + (size_t)s * 4;
    o[0] = lo;
    o[1] = hi;
    if (z > 0) {
        uint4* p = ws + (size_t)(s - 1) * 4;
        p[2] = lo;
        p[3] = hi;
    }
    if (z == GD - 1) {
        o[2] = lo;
        o[3] = hi;
    }
}

__global__ __launch_bounds__(256) void interp_pair_k(const uint4* __restrict__ ws,
                                                     const float* __restrict__ coords,
                                                     float* __restrict__ out, int N) {
    int n = blockIdx.x * 256 + threadIdx.x;
    if (n >= N) return;

    float cx = (coords[3 * n + 0] + 1.0f) * 0.5f * (float)(GD - 1);
    float cy = (coords[3 * n + 1] + 1.0f) * 0.5f * (float)(GD - 1);
    float cz = (coords[3 * n + 2] + 1.0f) * 0.5f * (float)(GD - 1);

    float fx = floorf(cx), fy = floorf(cy), fz = floorf(cz);
    float tx = cx - fx, ty = cy - fy, tz = cz - fz;
    int ix = (int)fx, iy = (int)fy, iz = (int)fz;

    int ix0 = min(max(ix,     0), GD - 1), ix1 = min(max(ix + 1, 0), GD - 1);
    int iy0 = min(max(iy,     0), GD - 1), iy1 = min(max(iy + 1, 0), GD - 1);
    int iz0 = min(max(iz,     0), GD - 1);

    float wx0 = 1.0f - tx, wx1 = tx;
    float wy0 = 1.0f - ty, wy1 = ty;
    float wz0 = 1.0f - tz, wz1 = tz;

    const uint4* p0 = ws + ((size_t)(ix0 * GD + iy0) * GD + iz0) * 4;
    const uint4* p1 = ws + ((size_t)(ix0 * GD + iy1) * GD + iz0) * 4;
    const uint4* p2 = ws + ((size_t)(ix1 * GD + iy0) * GD + iz0) * 4;
    const uint4* p3 = ws + ((size_t)(ix1 * GD + iy1) * GD + iz0) * 4;

    uint4 q[16];
#pragma unroll
    for (int j = 0; j < 4; ++j) {
        q[0 + j]  = p0[j];
        q[4 + j]  = p1[j];
        q[8 + j]  = p2[j];
        q[12 + j] = p3[j];
    }

    float wxy[4] = { wx0 * wy0, wx0 * wy1, wx1 * wy0, wx1 * wy1 };

    float acc[NCH];
#pragma unroll
    for (int c = 0; c < NCH; ++c) acc[c] = 0.0f;

#pragma unroll
    for (int r = 0; r < 4; ++r) {
        unsigned u0[8] = { q[4 * r + 0].x, q[4 * r + 0].y, q[4 * r + 0].z, q[4 * r + 0].w,
                           q[4 * r + 1].x, q[4 * r + 1].y, q[4 * r + 1].z, q[4 * r + 1].w };
        unsigned u1[8] = { q[4 * r + 2].x, q[4 * r + 2].y, q[4 * r + 2].z, q[4 * r + 2].w,
                           q[4 * r + 3].x, q[4 * r + 3].y, q[4 * r + 3].z, q[4 * r + 3].w };
        float wxyr = wxy[r];
#pragma unroll
        for (int k = 0; k < 8; ++k) {
            float z0lo = __builtin_bit_cast(float, u0[k] << 16);
            float z0hi = __builtin_bit_cast(float, u0[k] & 0xffff0000u);
            float z1lo = __builtin_bit_cast(float, u1[k] << 16);
            float z1hi = __builtin_bit_cast(float, u1[k] & 0xffff0000u);
            acc[2 * k + 0] += wxyr * (wz0 * z0lo + wz1 * z1lo);
            acc[2 * k + 1] += wxyr * (wz0 * z0hi + wz1 * z1hi);
        }
    }

#pragma unroll
    for (int c = 0; c < NCH; ++c)
        __builtin_nontemporal_store(acc[c], out + (size_t)c * N + n);
}

// ---------- last-resort fallback: direct gather from native layout (fp32) ----------
__global__ __launch_bounds__(256) void interp_direct_k(const float* __restrict__ in,
                                                       const float* __restrict__ coords,
                                                       float* __restrict__ out, int N) {
    int n = blockIdx.x * 256 + threadIdx.x;
    if (n >= N) return;
    float cx = (coords[3 * n + 0] + 1.0f) * 0.5f * (float)(GD - 1);
    float cy = (coords[3 * n + 1] + 1.0f) * 0.5f * (float)(GD - 1);
    float cz = (coords[3 * n + 2] + 1.0f) * 0.5f * (float)(GD - 1);
    float fx = floorf(cx), fy = floorf(cy), fz = floorf(cz);
    float tx = cx - fx, ty = cy - fy, tz = cz - fz;
    int ix = (int)fx, iy = (int)fy, iz = (int)fz;
    int ix0 = min(max(ix, 0), GD - 1), ix1 = min(max(ix + 1, 0), GD - 1);
    int iy0 = min(max(iy, 0), GD - 1), iy1 = min(max(iy + 1, 0), GD - 1);
    int iz0 = min(max(iz, 0), GD - 1), iz1 = min(max(iz + 1, 0), GD - 1);
    float wx0 = 1.0f - tx, wx1 = tx, wy0 = 1.0f - ty, wy1 = ty, wz0 = 1.0f - tz, wz1 = tz;
    int o000 = (ix0 * GD + iy0) * GD + iz0, o001 = (ix0 * GD + iy0) * GD + iz1;
    int o010 = (ix0 * GD + iy1) * GD + iz0, o011 = (ix0 * GD + iy1) * GD + iz1;
    int o100 = (ix1 * GD + iy0) * GD + iz0, o101 = (ix1 * GD + iy0) * GD + iz1;
    int o110 = (ix1 * GD + iy1) * GD + iz0, o111 = (ix1 * GD + iy1) * GD + iz1;
    float w000 = wx0 * wy0 * wz0, w001 = wx0 * wy0 * wz1;
    float w010 = wx0 * wy1 * wz0, w011 = wx0 * wy1 * wz1;
    float w100 = wx1 * wy0 * wz0, w101 = wx1 * wy0 * wz1;
    float w110 = wx1 * wy1 * wz0, w111 = wx1 * wy1 * wz1;
#pragma unroll
    for (int c = 0; c < NCH; ++c) {
        const float* g = in + (size_t)c * VOX;
        float acc = w000 * g[o000] + w001 * g[o001] + w010 * g[o010] + w011 * g[o011]
                  + w100 * g[o100] + w101 * g[o101] + w110 * g[o110] + w111 * g[o111];
        out[(size_t)c * N + n] = acc;
    }
}

extern "C" void kernel_launch(void* const* d_in, const int* in_sizes, int n_in,
                              void* d_out, int out_size, void* d_ws, size_t ws_size,
                              hipStream_t stream) {
    const float* input  = (const float*)d_in[0];
    const float* coords = (const float*)d_in[1];
    float* out = (float*)d_out;
    int N = in_sizes[1] / 3;  // 1,000,000
    int nb = (N + 255) / 256;

    size_t need_quad = (size_t)VOX * 128;  // 268,435,456 B quad layout
    size_t need_pair = (size_t)VOX * 64;   // 134,217,728 B pair layout
    if (ws_size >= need_quad) {
        transpose_quad_k<<<VOX / 256, 256, 0, stream>>>(input, (uint4*)d_ws);
        interp_quad_k<<<nb, 256, 0, stream>>>((const uint4*)d_ws, coords, out, N);
    } else if (ws_size >= need_pair) {
        transpose_half_k<<<VOX / 256, 256, 0, stream>>>(input, (uint4*)d_ws);
        interp_pair_k<<<nb, 256, 0, stream>>>((const uint4*)d_ws, coords, out, N);
    } else {
        interp_direct_k<<<nb, 256, 0, stream>>>(input, coords, out, N);
    }
}

// Round 4
// 304.149 us; speedup vs baseline: 1.3567x; 1.3567x over previous
//
#include <hip/hip_runtime.h>

// Trilinear interpolation: input [16][128][128][128] fp32, coords [N][3] in [-1,1],
// out [16][N] fp32.
//
// R8 (resubmit — previous round failed on container acquire, kernel never ran):
// revert to R6's 64 B pair layout (R7's 128 B quad cells lost: scattered 32 B
// writes made transpose transaction-bound at 165 us, and interp showed no gain ->
// the random-read wall is per-byte, not per-transaction).
//  - pair line s = 64 B = {16ch bf16 @ z, 16ch bf16 @ z+1 (clamped)}; interp reads
//    exactly 4 aligned 64 B lines/pt = 256 B payload floor.
//  - NEW transpose: LDS-assembled, fully-coalesced stores. Each block converts its
//    256 voxels (2 whole z-columns) to bf16 pairs in LDS (8 KB), then writes its
//    16 KB output region with lane-contiguous dwordx4 (1 KB/wave/instr), replacing
//    R6's 64 B-strided 16 B stores (4x transaction waste). The z+1 duplication is
//    an LDS broadcast re-read instead of a second global store stream.

#define GD   128
#define NCH  16
constexpr int VOX = GD * GD * GD;

__device__ __forceinline__ unsigned short f2bf_rne(float f) {
    unsigned u = __builtin_bit_cast(unsigned, f);
    u = u + 0x7fffu + ((u >> 16) & 1u);   // round-nearest-even
    return (unsigned short)(u >> 16);
}

// ---------- transpose: LDS staging, coalesced 64 B-line output ----------
__global__ __launch_bounds__(256) void transpose_pair_lds_k(const float* __restrict__ in,
                                                            uint4* __restrict__ ws) {
    __shared__ unsigned lds[256 * 8];   // 8 KB: 256 voxels x 16ch bf16
    int t  = threadIdx.x;
    int s0 = blockIdx.x * 256;          // block owns voxels [s0, s0+256) = 2 z-columns
    int s  = s0 + t;

    // 16 coalesced NT dword loads, all batched for MLP
    float a[NCH];
#pragma unroll
    for (int c = 0; c < NCH; ++c)
        a[c] = __builtin_nontemporal_load(in + (size_t)c * VOX + s);

#pragma unroll
    for (int k = 0; k < 8; ++k)
        lds[t * 8 + k] = (unsigned)f2bf_rne(a[2 * k + 0])
                       | ((unsigned)f2bf_rne(a[2 * k + 1]) << 16);

    __syncthreads();

    // emit block's 1024 output uint4s: lane-contiguous stores, LDS-sourced.
    // line l (l = g>>2): slots {lo(z), hi(z), lo(z+1 clamped), hi(z+1 clamped)}
    const uint4* l4 = (const uint4*)lds;       // voxel v = uint4s {2v, 2v+1}
    uint4* o = ws + (size_t)s0 * 4;
#pragma unroll
    for (int k = 0; k < 4; ++k) {
        int g    = t + 256 * k;
        int line = g >> 2;                     // 0..255 within block
        int col  = line >> 7;                  // which z-column (0/1)
        int z    = line & (GD - 1);
        int slot = g & 3;
        int vz   = min(z + (slot >> 1), GD - 1);   // slot 2/3 -> z+1, clamped
        o[g] = l4[(col * GD + vz) * 2 + (slot & 1)];
    }
}

// ---------- interp: 4 corner-lines x 64 B, all 16 loads batched (R6, unchanged) ----------
__global__ __launch_bounds__(256) void interp_pair_k(const uint4* __restrict__ ws,
                                                     const float* __restrict__ coords,
                                                     float* __restrict__ out, int N) {
    int n = blockIdx.x * 256 + threadIdx.x;
    if (n >= N) return;

    float cx = (coords[3 * n + 0] + 1.0f) * 0.5f * (float)(GD - 1);
    float cy = (coords[3 * n + 1] + 1.0f) * 0.5f * (float)(GD - 1);
    float cz = (coords[3 * n + 2] + 1.0f) * 0.5f * (float)(GD - 1);

    float fx = floorf(cx), fy = floorf(cy), fz = floorf(cz);
    float tx = cx - fx, ty = cy - fy, tz = cz - fz;
    int ix = (int)fx, iy = (int)fy, iz = (int)fz;

    int ix0 = min(max(ix,     0), GD - 1), ix1 = min(max(ix + 1, 0), GD - 1);
    int iy0 = min(max(iy,     0), GD - 1), iy1 = min(max(iy + 1, 0), GD - 1);
    int iz0 = min(max(iz,     0), GD - 1);
    // pair line at iz0 holds z=iz0 and z=min(iz0+1, GD-1) == clamped iz1. exact.

    float wx0 = 1.0f - tx, wx1 = tx;
    float wy0 = 1.0f - ty, wy1 = ty;
    float wz0 = 1.0f - tz, wz1 = tz;

    const uint4* p0 = ws + ((size_t)(ix0 * GD + iy0) * GD + iz0) * 4;
    const uint4* p1 = ws + ((size_t)(ix0 * GD + iy1) * GD + iz0) * 4;
    const uint4* p2 = ws + ((size_t)(ix1 * GD + iy0) * GD + iz0) * 4;
    const uint4* p3 = ws + ((size_t)(ix1 * GD + iy1) * GD + iz0) * 4;

    // batch ALL 16 line-loads up front: maximal MLP per wave
    uint4 q[16];
#pragma unroll
    for (int j = 0; j < 4; ++j) {
        q[0 + j]  = p0[j];
        q[4 + j]  = p1[j];
        q[8 + j]  = p2[j];
        q[12 + j] = p3[j];
    }

    float wxy[4] = { wx0 * wy0, wx0 * wy1, wx1 * wy0, wx1 * wy1 };

    float acc[NCH];
#pragma unroll
    for (int c = 0; c < NCH; ++c) acc[c] = 0.0f;

#pragma unroll
    for (int r = 0; r < 4; ++r) {
        unsigned u0[8] = { q[4 * r + 0].x, q[4 * r + 0].y, q[4 * r + 0].z, q[4 * r + 0].w,
                           q[4 * r + 1].x, q[4 * r + 1].y, q[4 * r + 1].z, q[4 * r + 1].w };
        unsigned u1[8] = { q[4 * r + 2].x, q[4 * r + 2].y, q[4 * r + 2].z, q[4 * r + 2].w,
                           q[4 * r + 3].x, q[4 * r + 3].y, q[4 * r + 3].z, q[4 * r + 3].w };
        float wxyr = wxy[r];
#pragma unroll
        for (int k = 0; k < 8; ++k) {
            float z0lo = __builtin_bit_cast(float, u0[k] << 16);
            float z0hi = __builtin_bit_cast(float, u0[k] & 0xffff0000u);
            float z1lo = __builtin_bit_cast(float, u1[k] << 16);
            float z1hi = __builtin_bit_cast(float, u1[k] & 0xffff0000u);
            acc[2 * k + 0] += wxyr * (wz0 * z0lo + wz1 * z1lo);
            acc[2 * k + 1] += wxyr * (wz0 * z0hi + wz1 * z1hi);
        }
    }

#pragma unroll
    for (int c = 0; c < NCH; ++c)
        __builtin_nontemporal_store(acc[c], out + (size_t)c * N + n);  // never re-read
}

// ---------- fallback: direct gather from native layout (fp32) ----------
__global__ __launch_bounds__(256) void interp_direct_k(const float* __restrict__ in,
                                                       const float* __restrict__ coords,
                                                       float* __restrict__ out, int N) {
    int n = blockIdx.x * 256 + threadIdx.x;
    if (n >= N) return;
    float cx = (coords[3 * n + 0] + 1.0f) * 0.5f * (float)(GD - 1);
    float cy = (coords[3 * n + 1] + 1.0f) * 0.5f * (float)(GD - 1);
    float cz = (coords[3 * n + 2] + 1.0f) * 0.5f * (float)(GD - 1);
    float fx = floorf(cx), fy = floorf(cy), fz = floorf(cz);
    float tx = cx - fx, ty = cy - fy, tz = cz - fz;
    int ix = (int)fx, iy = (int)fy, iz = (int)fz;
    int ix0 = min(max(ix, 0), GD - 1), ix1 = min(max(ix + 1, 0), GD - 1);
    int iy0 = min(max(iy, 0), GD - 1), iy1 = min(max(iy + 1, 0), GD - 1);
    int iz0 = min(max(iz, 0), GD - 1), iz1 = min(max(iz + 1, 0), GD - 1);
    float wx0 = 1.0f - tx, wx1 = tx, wy0 = 1.0f - ty, wy1 = ty, wz0 = 1.0f - tz, wz1 = tz;
    int o000 = (ix0 * GD + iy0) * GD + iz0, o001 = (ix0 * GD + iy0) * GD + iz1;
    int o010 = (ix0 * GD + iy1) * GD + iz0, o011 = (ix0 * GD + iy1) * GD + iz1;
    int o100 = (ix1 * GD + iy0) * GD + iz0, o101 = (ix1 * GD + iy0) * GD + iz1;
    int o110 = (ix1 * GD + iy1) * GD + iz0, o111 = (ix1 * GD + iy1) * GD + iz1;
    float w000 = wx0 * wy0 * wz0, w001 = wx0 * wy0 * wz1;
    float w010 = wx0 * wy1 * wz0, w011 = wx0 * wy1 * wz1;
    float w100 = wx1 * wy0 * wz0, w101 = wx1 * wy0 * wz1;
    float w110 = wx1 * wy1 * wz0, w111 = wx1 * wy1 * wz1;
#pragma unroll
    for (int c = 0; c < NCH; ++c) {
        const float* g = in + (size_t)c * VOX;
        float acc = w000 * g[o000] + w001 * g[o001] + w010 * g[o010] + w011 * g[o011]
                  + w100 * g[o100] + w101 * g[o101] + w110 * g[o110] + w111 * g[o111];
        out[(size_t)c * N + n] = acc;
    }
}

extern "C" void kernel_launch(void* const* d_in, const int* in_sizes, int n_in,
                              void* d_out, int out_size, void* d_ws, size_t ws_size,
                              hipStream_t stream) {
    const float* input  = (const float*)d_in[0];
    const float* coords = (const float*)d_in[1];
    float* out = (float*)d_out;
    int N = in_sizes[1] / 3;  // 1,000,000
    int nb = (N + 255) / 256;

    size_t need = (size_t)VOX * 64;  // 134,217,728 B pair layout
    if (ws_size >= need) {
        transpose_pair_lds_k<<<VOX / 256, 256, 0, stream>>>(input, (uint4*)d_ws);
        interp_pair_k<<<nb, 256, 0, stream>>>((const uint4*)d_ws, coords, out, N);
    } else {
        interp_direct_k<<<nb, 256, 0, stream>>>(input, coords, out, N);
    }
}

// Round 6
// 302.754 us; speedup vs baseline: 1.3630x; 1.0046x over previous
//
#include <hip/hip_runtime.h>

// Trilinear interpolation: input [16][128][128][128] fp32, coords [N][3] in [-1,1],
// out [16][N] fp32.
//
// R9b (compile fix: __builtin_nontemporal_load needs a clang ext_vector_type, not
// HIP_vector_type float4): keep R6/R8's 64 B pair layout + interp (measured at the
// random-access per-byte wall: 256 B/pt payload floor @ ~3.6 TB/s; R7 proved
// bigger transactions don't lift the rate). Transpose with WIDE input reads:
//  - block = 256 thr handles 1024 voxels (8 whole z-columns, s0 1024-aligned).
//  - thread t: 16x NT dwordx4 loads (1 KB/wave/instr, 4x fewer load instrs than
//    R8's scalar dwords) -> owns ALL 16 channels of 4 consecutive voxels.
//  - pack bf16 pairs into 32 KB LDS, sync, emit 64 KB of pair lines with
//    lane-contiguous dwordx4 stores (z+1 duplication = LDS re-read).

#define GD   128
#define NCH  16
constexpr int VOX = GD * GD * GD;

typedef float vf4 __attribute__((ext_vector_type(4)));

__device__ __forceinline__ unsigned short f2bf_rne(float f) {
    unsigned u = __builtin_bit_cast(unsigned, f);
    u = u + 0x7fffu + ((u >> 16) & 1u);   // round-nearest-even
    return (unsigned short)(u >> 16);
}

// ---------- transpose: dwordx4 reads, LDS staging, coalesced 64 B-line output ----------
__global__ __launch_bounds__(256) void transpose_pair_v4_k(const float* __restrict__ in,
                                                           uint4* __restrict__ ws) {
    __shared__ unsigned lds[1024 * 8];   // 32 KB: 1024 voxels x 16ch bf16
    int t  = threadIdx.x;
    int s0 = blockIdx.x * 1024;          // block owns voxels [s0, s0+1024) = 8 z-columns

    // 16 batched NT dwordx4 loads: channel c, voxels s0+4t .. s0+4t+3
    vf4 a[NCH];
#pragma unroll
    for (int c = 0; c < NCH; ++c)
        a[c] = __builtin_nontemporal_load(
            (const vf4*)(in + (size_t)c * VOX + s0) + t);

    // pack: voxel j (of this thread's 4) -> 8 uints of 16 bf16 channels
#pragma unroll
    for (int j = 0; j < 4; ++j) {
        unsigned* dst = lds + (4 * t + j) * 8;
#pragma unroll
        for (int k = 0; k < 8; ++k) {
            dst[k] = (unsigned)f2bf_rne(a[2 * k][j])
                   | ((unsigned)f2bf_rne(a[2 * k + 1][j]) << 16);
        }
    }

    __syncthreads();

    // emit block's 4096 output uint4s (64 KB): lane-contiguous stores.
    // line l: slots {lo(z), hi(z), lo(z+1 clamped), hi(z+1 clamped)}
    const uint4* l4 = (const uint4*)lds;       // local voxel v = uint4s {2v, 2v+1}
    uint4* o = ws + (size_t)s0 * 4;
#pragma unroll
    for (int g = 0; g < 16; ++g) {
        int idx  = t + 256 * g;                // 0..4095
        int line = idx >> 2;                   // 0..1023 within block
        int col  = line >> 7;                  // which z-column (0..7)
        int z    = line & (GD - 1);
        int slot = idx & 3;
        int vz   = min(z + (slot >> 1), GD - 1);   // slot 2/3 -> z+1, clamped
        o[idx] = l4[(col * GD + vz) * 2 + (slot & 1)];
    }
}

// ---------- interp: 4 corner-lines x 64 B, all 16 loads batched (unchanged) ----------
__global__ __launch_bounds__(256) void interp_pair_k(const uint4* __restrict__ ws,
                                                     const float* __restrict__ coords,
                                                     float* __restrict__ out, int N) {
    int n = blockIdx.x * 256 + threadIdx.x;
    if (n >= N) return;

    float cx = (coords[3 * n + 0] + 1.0f) * 0.5f * (float)(GD - 1);
    float cy = (coords[3 * n + 1] + 1.0f) * 0.5f * (float)(GD - 1);
    float cz = (coords[3 * n + 2] + 1.0f) * 0.5f * (float)(GD - 1);

    float fx = floorf(cx), fy = floorf(cy), fz = floorf(cz);
    float tx = cx - fx, ty = cy - fy, tz = cz - fz;
    int ix = (int)fx, iy = (int)fy, iz = (int)fz;

    int ix0 = min(max(ix,     0), GD - 1), ix1 = min(max(ix + 1, 0), GD - 1);
    int iy0 = min(max(iy,     0), GD - 1), iy1 = min(max(iy + 1, 0), GD - 1);
    int iz0 = min(max(iz,     0), GD - 1);
    // pair line at iz0 holds z=iz0 and z=min(iz0+1, GD-1) == clamped iz1. exact.

    float wx0 = 1.0f - tx, wx1 = tx;
    float wy0 = 1.0f - ty, wy1 = ty;
    float wz0 = 1.0f - tz, wz1 = tz;

    const uint4* p0 = ws + ((size_t)(ix0 * GD + iy0) * GD + iz0) * 4;
    const uint4* p1 = ws + ((size_t)(ix0 * GD + iy1) * GD + iz0) * 4;
    const uint4* p2 = ws + ((size_t)(ix1 * GD + iy0) * GD + iz0) * 4;
    const uint4* p3 = ws + ((size_t)(ix1 * GD + iy1) * GD + iz0) * 4;

    // batch ALL 16 line-loads up front: maximal MLP per wave
    uint4 q[16];
#pragma unroll
    for (int j = 0; j < 4; ++j) {
        q[0 + j]  = p0[j];
        q[4 + j]  = p1[j];
        q[8 + j]  = p2[j];
        q[12 + j] = p3[j];
    }

    float wxy[4] = { wx0 * wy0, wx0 * wy1, wx1 * wy0, wx1 * wy1 };

    float acc[NCH];
#pragma unroll
    for (int c = 0; c < NCH; ++c) acc[c] = 0.0f;

#pragma unroll
    for (int r = 0; r < 4; ++r) {
        unsigned u0[8] = { q[4 * r + 0].x, q[4 * r + 0].y, q[4 * r + 0].z, q[4 * r + 0].w,
                           q[4 * r + 1].x, q[4 * r + 1].y, q[4 * r + 1].z, q[4 * r + 1].w };
        unsigned u1[8] = { q[4 * r + 2].x, q[4 * r + 2].y, q[4 * r + 2].z, q[4 * r + 2].w,
                           q[4 * r + 3].x, q[4 * r + 3].y, q[4 * r + 3].z, q[4 * r + 3].w };
        float wxyr = wxy[r];
#pragma unroll
        for (int k = 0; k < 8; ++k) {
            float z0lo = __builtin_bit_cast(float, u0[k] << 16);
            float z0hi = __builtin_bit_cast(float, u0[k] & 0xffff0000u);
            float z1lo = __builtin_bit_cast(float, u1[k] << 16);
            float z1hi = __builtin_bit_cast(float, u1[k] & 0xffff0000u);
            acc[2 * k + 0] += wxyr * (wz0 * z0lo + wz1 * z1lo);
            acc[2 * k + 1] += wxyr * (wz0 * z0hi + wz1 * z1hi);
        }
    }

#pragma unroll
    for (int c = 0; c < NCH; ++c)
        __builtin_nontemporal_store(acc[c], out + (size_t)c * N + n);  // never re-read
}

// ---------- fallback: direct gather from native layout (fp32) ----------
__global__ __launch_bounds__(256) void interp_direct_k(const float* __restrict__ in,
                                                       const float* __restrict__ coords,
                                                       float* __restrict__ out, int N) {
    int n = blockIdx.x * 256 + threadIdx.x;
    if (n >= N) return;
    float cx = (coords[3 * n + 0] + 1.0f) * 0.5f * (float)(GD - 1);
    float cy = (coords[3 * n + 1] + 1.0f) * 0.5f * (float)(GD - 1);
    float cz = (coords[3 * n + 2] + 1.0f) * 0.5f * (float)(GD - 1);
    float fx = floorf(cx), fy = floorf(cy), fz = floorf(cz);
    float tx = cx - fx, ty = cy - fy, tz = cz - fz;
    int ix = (int)fx, iy = (int)fy, iz = (int)fz;
    int ix0 = min(max(ix, 0), GD - 1), ix1 = min(max(ix + 1, 0), GD - 1);
    int iy0 = min(max(iy, 0), GD - 1), iy1 = min(max(iy + 1, 0), GD - 1);
    int iz0 = min(max(iz, 0), GD - 1), iz1 = min(max(iz + 1, 0), GD - 1);
    float wx0 = 1.0f - tx, wx1 = tx, wy0 = 1.0f - ty, wy1 = ty, wz0 = 1.0f - tz, wz1 = tz;
    int o000 = (ix0 * GD + iy0) * GD + iz0, o001 = (ix0 * GD + iy0) * GD + iz1;
    int o010 = (ix0 * GD + iy1) * GD + iz0, o011 = (ix0 * GD + iy1) * GD + iz1;
    int o100 = (ix1 * GD + iy0) * GD + iz0, o101 = (ix1 * GD + iy0) * GD + iz1;
    int o110 = (ix1 * GD + iy1) * GD + iz0, o111 = (ix1 * GD + iy1) * GD + iz1;
    float w000 = wx0 * wy0 * wz0, w001 = wx0 * wy0 * wz1;
    float w010 = wx0 * wy1 * wz0, w011 = wx0 * wy1 * wz1;
    float w100 = wx1 * wy0 * wz0, w101 = wx1 * wy0 * wz1;
    float w110 = wx1 * wy1 * wz0, w111 = wx1 * wy1 * wz1;
#pragma unroll
    for (int c = 0; c < NCH; ++c) {
        const float* g = in + (size_t)c * VOX;
        float acc = w000 * g[o000] + w001 * g[o001] + w010 * g[o010] + w011 * g[o011]
                  + w100 * g[o100] + w101 * g[o101] + w110 * g[o110] + w111 * g[o111];
        out[(size_t)c * N + n] = acc;
    }
}

extern "C" void kernel_launch(void* const* d_in, const int* in_sizes, int n_in,
                              void* d_out, int out_size, void* d_ws, size_t ws_size,
                              hipStream_t stream) {
    const float* input  = (const float*)d_in[0];
    const float* coords = (const float*)d_in[1];
    float* out = (float*)d_out;
    int N = in_sizes[1] / 3;  // 1,000,000
    int nb = (N + 255) / 256;

    size_t need = (size_t)VOX * 64;  // 134,217,728 B pair layout
    if (ws_size >= need) {
        transpose_pair_v4_k<<<VOX / 1024, 256, 0, stream>>>(input, (uint4*)d_ws);
        interp_pair_k<<<nb, 256, 0, stream>>>((const uint4*)d_ws, coords, out, N);
    } else {
        interp_direct_k<<<nb, 256, 0, stream>>>(input, coords, out, N);
    }
}